// Round 4
// baseline (130.430 us; speedup 1.0000x reference)
//
#include <hip/hip_runtime.h>
#include <math.h>

typedef __attribute__((ext_vector_type(8))) short bf16x8;
typedef __attribute__((ext_vector_type(4))) float f32x4;

#define MFMA(a, b, c) __builtin_amdgcn_mfma_f32_16x16x32_bf16(a, b, c, 0, 0, 0)

constexpr int GN = 128;   // B*T
constexpr int NN = 512;   // nodes
constexpr int FD = 128;   // F_in == D == 128
#define LOG2E 1.4426950408889634f

// round-to-nearest-even bf16 kept in the TOP 16 bits of a u32
__device__ inline unsigned rne_top16(float x) {
    unsigned u = __float_as_uint(x);
    return u + 0x7fffu + ((u >> 16) & 1u);
}
// pack top-16 of e0 (-> low half) and e1 (-> high half)
__device__ inline unsigned pack_top16(unsigned e1, unsigned e0) {
    return __builtin_amdgcn_perm(e1, e0, 0x07060302u);
}

// ---------------------------------------------------------------------------
// ONE fused kernel. 256 blocks = (g, half), 1024 threads (16 waves).
// R3 post-mortem: 16 waves => <=128 unified regs/wave; acc eats 64 AGPR =>
// only 64 arch VGPRs => compiler can't pipeline across KK. This version cuts
// phase-2 register demand (adj int4 prefetch -> LDS bitmask) and adds an
// explicit P-pipeline skew (compute P[KK+1] VALU while MFMAs of KK drain),
// plus setprio around the MFMA cluster and a balanced epilogue.
//
// Phase 0 (prologue): issue h(kk=0) + W loads; build maskS (256 rows x 16
//   words, stride 17) from adj via int4+bit-or; W fp32 -> hi/lo bf16 split
//   swizzled into sWh upper half (dead until transpose).
// Phase 1: full Wh[g] = h@W via 3-split bf16 MFMA, 16 waves x 32 rows,
//   barrier-free K loop. esrc/edst (x LOG2E) -> LDS. Transpose Wh into
//   B-frag-swizzled sWh (single RNE bf16).
// Phase 2: wave pairs (rg = w>>1 owns 32 i-rows, jh = w&1 owns 8 KK).
//   Pipelined: computeP(KK+1) before MFMA(KK); mask from 2 ds_read_b32;
//   lsum via ones-column MFMA. Epilogue: jh=0 finalizes mt0 tile, jh=1
//   finalizes mt1 (balanced); partial exchange through sWh-as-float.
// ---------------------------------------------------------------------------
__global__ __launch_bounds__(1024) void gat_fused_kernel(
    const float* __restrict__ h, const float* __restrict__ a,
    const int* __restrict__ adj, const float* __restrict__ W,
    float* __restrict__ out)
{
    __shared__ __attribute__((aligned(16))) unsigned short sWh[65536]; // 128 KB
    __shared__ unsigned maskS[4352];                                   // 17 KB
    __shared__ __attribute__((aligned(16))) float sEsrc[NN];           // 2 KB
    __shared__ __attribute__((aligned(16))) float sEdst[NN];           // 2 KB

    const int bid = blockIdx.x;
    const int xcd = bid & 7, slot = bid >> 3;
    const int g  = xcd * 16 + (slot >> 1);   // both halves of g on one XCD
    const int hf = slot & 1;
    const int t = threadIdx.x, lane = t & 63, w = t >> 6;   // w in [0,16)
    const int l15 = lane & 15, q8 = (lane >> 4) * 8;
    const float* hg = h + (size_t)g * NN * FD;

    // ---- issue h loads for kk=0 (front-load HBM latency) ----
    float4 hv0[4];
    #pragma unroll
    for (int mt = 0; mt < 2; ++mt) {
        const float* src = hg + (size_t)(w * 32 + mt * 16 + l15) * FD + q8;
        hv0[2 * mt]     = *(const float4*)src;
        hv0[2 * mt + 1] = *(const float4*)(src + 4);
    }

    // ---- issue W loads (L2/L3-resident) ----
    float wv[16];
    {
        #pragma unroll
        for (int rep = 0; rep < 2; ++rep) {
            const int p = rep * 1024 + t;
            const int lanep = p & 63, cn2 = p >> 6;        // cn2 = kk*8+nb
            const int kbase = (cn2 >> 3) * 32 + ((lanep >> 4) & 3) * 8;
            const int d = (cn2 & 7) * 16 + (lanep & 15);
            #pragma unroll
            for (int idx = 0; idx < 8; ++idx)
                wv[rep * 8 + idx] = W[(kbase + idx) * FD + d];
        }
    }

    // ---- build maskS: 4 words per thread (R0 prep pattern) ----
    #pragma unroll
    for (int q = 0; q < 4; ++q) {
        const int wi = t * 4 + q;                  // 0..4095
        const int row = wi >> 4, wo = wi & 15;     // local row, word
        const int* p = adj + (size_t)(hf * 256 + row) * NN + wo * 32;
        unsigned m = 0;
        #pragma unroll
        for (int b = 0; b < 32; b += 4) {
            const int4 v = *(const int4*)&p[b];
            m |= (v.x > 0 ? 1u : 0u) << b;
            m |= (v.y > 0 ? 1u : 0u) << (b + 1);
            m |= (v.z > 0 ? 1u : 0u) << (b + 2);
            m |= (v.w > 0 ? 1u : 0u) << (b + 3);
        }
        maskS[row * 17 + wo] = m;
    }

    // ---- W hi/lo split -> swizzled sWh upper half ----
    #pragma unroll
    for (int rep = 0; rep < 2; ++rep) {
        const int p = rep * 1024 + t;
        unsigned hi[8], lo[8];
        #pragma unroll
        for (int idx = 0; idx < 8; ++idx) {
            const unsigned u = __float_as_uint(wv[rep * 8 + idx]);
            hi[idx] = u;                               // top16 = truncation
            lo[idx] = rne_top16(wv[rep * 8 + idx] - __uint_as_float(u & 0xffff0000u));
        }
        uint4 H4, L4;
        H4.x = pack_top16(hi[1], hi[0]); H4.y = pack_top16(hi[3], hi[2]);
        H4.z = pack_top16(hi[5], hi[4]); H4.w = pack_top16(hi[7], hi[6]);
        L4.x = pack_top16(lo[1], lo[0]); L4.y = pack_top16(lo[3], lo[2]);
        L4.z = pack_top16(lo[5], lo[4]); L4.w = pack_top16(lo[7], lo[6]);
        *(uint4*)&sWh[32768 + p * 8] = H4;
        *(uint4*)&sWh[49152 + p * 8] = L4;
    }
    __syncthreads();

    // ================= phase 1: Wh[g], barrier-free K loop =================
    f32x4 acc1[2][8];
    #pragma unroll
    for (int mt = 0; mt < 2; ++mt)
        #pragma unroll
        for (int nb = 0; nb < 8; ++nb) acc1[mt][nb] = (f32x4){0.f, 0.f, 0.f, 0.f};

    #pragma unroll
    for (int kk = 0; kk < 4; ++kk) {
        float4 hv[4];
        if (kk == 0) {
            #pragma unroll
            for (int q = 0; q < 4; ++q) hv[q] = hv0[q];
        } else {
            #pragma unroll
            for (int mt = 0; mt < 2; ++mt) {
                const float* src = hg + (size_t)(w * 32 + mt * 16 + l15) * FD
                                 + kk * 32 + q8;
                hv[2 * mt]     = *(const float4*)src;
                hv[2 * mt + 1] = *(const float4*)(src + 4);
            }
        }
        bf16x8 ah[2], al[2];
        #pragma unroll
        for (int mt = 0; mt < 2; ++mt) {
            const float4 f0 = hv[2 * mt], f1 = hv[2 * mt + 1];
            const float xs[8] = {f0.x, f0.y, f0.z, f0.w, f1.x, f1.y, f1.z, f1.w};
            union { bf16x8 v; unsigned u[4]; } H, L;
            #pragma unroll
            for (int j = 0; j < 4; ++j) {
                const unsigned e0 = __float_as_uint(xs[2 * j]);
                const unsigned e1 = __float_as_uint(xs[2 * j + 1]);
                H.u[j] = pack_top16(e1, e0);
                const unsigned l0 = rne_top16(xs[2*j]   - __uint_as_float(e0 & 0xffff0000u));
                const unsigned l1 = rne_top16(xs[2*j+1] - __uint_as_float(e1 & 0xffff0000u));
                L.u[j] = pack_top16(l1, l0);
            }
            ah[mt] = H.v; al[mt] = L.v;
        }
        #pragma unroll
        for (int nb = 0; nb < 8; ++nb) {
            const bf16x8 bh = *(const bf16x8*)&sWh[32768 + ((kk * 8 + nb) * 64 + lane) * 8];
            const bf16x8 bl = *(const bf16x8*)&sWh[49152 + ((kk * 8 + nb) * 64 + lane) * 8];
            #pragma unroll
            for (int mt = 0; mt < 2; ++mt) {
                acc1[mt][nb] = MFMA(al[mt], bh, acc1[mt][nb]);
                acc1[mt][nb] = MFMA(ah[mt], bl, acc1[mt][nb]);
                acc1[mt][nb] = MFMA(ah[mt], bh, acc1[mt][nb]);
            }
        }
    }

    // ---- esrc / edst for this wave's 32 rows -> LDS (pre-scaled LOG2E) ----
    {
        float av[8], bv[8];
        #pragma unroll
        for (int nb = 0; nb < 8; ++nb) {
            av[nb] = a[nb * 16 + l15];
            bv[nb] = a[FD + nb * 16 + l15];
        }
        #pragma unroll
        for (int mt = 0; mt < 2; ++mt)
            #pragma unroll
            for (int r = 0; r < 4; ++r) {
                float ps = 0.f, pd = 0.f;
                #pragma unroll
                for (int nb = 0; nb < 8; ++nb) {
                    ps += acc1[mt][nb][r] * av[nb];
                    pd += acc1[mt][nb][r] * bv[nb];
                }
                #pragma unroll
                for (int off = 1; off <= 8; off <<= 1) {
                    ps += __shfl_xor(ps, off);
                    pd += __shfl_xor(pd, off);
                }
                if (l15 == 0) {
                    const int row = w * 32 + mt * 16 + (lane >> 4) * 4 + r;
                    sEsrc[row] = ps * LOG2E;
                    sEdst[row] = pd * LOG2E;
                }
            }
    }
    __syncthreads();   // all waves done reading W region of sWh

    // ---- transpose this wave's 32 Wh rows into swizzled sWh (RNE bf16) ----
    {
        const int ib = 4 * ((lane >> 4) & 1);
        #pragma unroll
        for (int mt = 0; mt < 2; ++mt) {
            const int lp2 = l15 + 16 * (mt * 2 + (lane >> 5));
            #pragma unroll
            for (int nb = 0; nb < 8; ++nb) {
                const int off = ((w * 8 + nb) * 64 + lp2) * 8 + ib;
                const unsigned r0 = rne_top16(acc1[mt][nb][0]);
                const unsigned r1 = rne_top16(acc1[mt][nb][1]);
                const unsigned r2 = rne_top16(acc1[mt][nb][2]);
                const unsigned r3 = rne_top16(acc1[mt][nb][3]);
                *(uint2*)&sWh[off] = make_uint2(pack_top16(r1, r0), pack_top16(r3, r2));
            }
        }
    }
    __syncthreads();   // sWh / sEsrc / sEdst / maskS complete

    // ================= phase 2: attention, pipelined =================
    const int rg = w >> 1, jh = w & 1;
    const int rloc0 = rg * 32 + l15;                 // within the 256-half
    const int rloc1 = rloc0 + 16;
    const float s0 = sEsrc[hf * 256 + rloc0 - 0 + (hf ? 0 : 0)] * 0.f + sEsrc[hf * 256 + rloc0];
    const float s1 = sEsrc[hf * 256 + rloc1];

    // register-constant B fragment: ones in column 0 (lane&15==0), else 0
    union { bf16x8 v; unsigned short s[8]; } bo;
    {
        const unsigned short oneb = (l15 == 0) ? (unsigned short)0x3f80 : (unsigned short)0;
        #pragma unroll
        for (int j = 0; j < 8; ++j) bo.s[j] = oneb;
    }

    f32x4 acc[2][8];
    #pragma unroll
    for (int mt = 0; mt < 2; ++mt)
        #pragma unroll
        for (int nb = 0; nb < 8; ++nb) acc[mt][nb] = (f32x4){0.f, 0.f, 0.f, 0.f};
    f32x4 accS0 = (f32x4){0.f, 0.f, 0.f, 0.f};
    f32x4 accS1 = (f32x4){0.f, 0.f, 0.f, 0.f};

    union PU { bf16x8 v; unsigned u[4]; };
    PU H0a, H1a, H0b, H1b;

    auto computeP = [&](const int KK, PU& H0, PU& H1) {
        const unsigned mw0 = maskS[rloc0 * 17 + KK] >> q8;
        const unsigned mw1 = maskS[rloc1 * 17 + KK] >> q8;
        const float* ep = &sEdst[KK * 32 + q8];
        const float4 ed0 = *(const float4*)ep;
        const float4 ed1 = *(const float4*)(ep + 4);
        const float ev[8] = {ed0.x, ed0.y, ed0.z, ed0.w, ed1.x, ed1.y, ed1.z, ed1.w};
        unsigned uh0[8], uh1[8];
        #pragma unroll
        for (int i = 0; i < 8; ++i) {
            const float z0 = s0 + ev[i];
            float p0 = __builtin_amdgcn_exp2f(fmaxf(z0, 0.2f * z0));
            p0 = ((mw0 >> i) & 1u) ? p0 : 0.f;
            uh0[i] = __float_as_uint(p0);
            const float z1 = s1 + ev[i];
            float p1 = __builtin_amdgcn_exp2f(fmaxf(z1, 0.2f * z1));
            p1 = ((mw1 >> i) & 1u) ? p1 : 0.f;
            uh1[i] = __float_as_uint(p1);
        }
        #pragma unroll
        for (int j = 0; j < 4; ++j) {
            H0.u[j] = pack_top16(uh0[2*j+1], uh0[2*j]);   // perm keeps top16 = trunc
            H1.u[j] = pack_top16(uh1[2*j+1], uh1[2*j]);
        }
    };

    const int k0 = jh * 8;                           // this wave's KK range
    computeP(k0, H0a, H1a);                          // prologue P

    #pragma unroll
    for (int kl = 0; kl < 8; ++kl) {
        const int KK = k0 + kl;
        PU& H0c = (kl & 1) ? H0b : H0a;
        PU& H1c = (kl & 1) ? H1b : H1a;
        PU& H0n = (kl & 1) ? H0a : H0b;
        PU& H1n = (kl & 1) ? H1a : H1b;
        if (kl < 7) computeP(KK + 1, H0n, H1n);      // VALU overlaps MFMAs below

        __builtin_amdgcn_s_setprio(1);
        #pragma unroll
        for (int nb = 0; nb < 8; ++nb) {
            const bf16x8 bh = *(const bf16x8*)&sWh[((KK * 8 + nb) * 64 + lane) * 8];
            acc[0][nb] = MFMA(H0c.v, bh, acc[0][nb]);
            acc[1][nb] = MFMA(H1c.v, bh, acc[1][nb]);
        }
        accS0 = MFMA(H0c.v, bo.v, accS0);            // row-sums (lsum) in col 0
        accS1 = MFMA(H1c.v, bo.v, accS1);
        __builtin_amdgcn_s_setprio(0);
    }

    __syncthreads();   // ALL waves done reading sWh (about to overwrite it)

    // ---- balanced epilogue: jh finalizes tile mt=jh, dumps tile mt=jh^1 ----
    float* sPartF = (float*)sWh;               // 32768 floats = 128 KB
    if (jh == 0) {
        #pragma unroll
        for (int nb = 0; nb < 8; ++nb)
            *(f32x4*)&sPartF[(((rg * 2 + 1) * 8 + nb) * 64 + lane) * 4] = acc[1][nb];
        if (l15 == 0) {
            #pragma unroll
            for (int r = 0; r < 4; ++r)
                sEsrc[rg * 32 + 16 + (lane >> 4) * 4 + r] = accS1[r];
        }
    } else {
        #pragma unroll
        for (int nb = 0; nb < 8; ++nb)
            *(f32x4*)&sPartF[(((rg * 2 + 0) * 8 + nb) * 64 + lane) * 4] = acc[0][nb];
        if (l15 == 0) {
            #pragma unroll
            for (int r = 0; r < 4; ++r)
                sEsrc[rg * 32 + (lane >> 4) * 4 + r] = accS0[r];
        }
    }
    __syncthreads();

    if (jh == 0) {
        #pragma unroll
        for (int nb = 0; nb < 8; ++nb) {
            const f32x4 p = *(const f32x4*)&sPartF[(((rg * 2 + 0) * 8 + nb) * 64 + lane) * 4];
            acc[0][nb][0] += p[0]; acc[0][nb][1] += p[1];
            acc[0][nb][2] += p[2]; acc[0][nb][3] += p[3];
        }
        #pragma unroll
        for (int r = 0; r < 4; ++r) {
            const float rl = 1.0f / (__shfl(accS0[r], lane & 48)
                                     + sEsrc[rg * 32 + (lane >> 4) * 4 + r]);
            const int row = g * NN + hf * 256 + rg * 32 + (lane >> 4) * 4 + r;
            #pragma unroll
            for (int nb = 0; nb < 8; ++nb)
                out[row * FD + nb * 16 + l15] = acc[0][nb][r] * rl;
        }
    } else {
        #pragma unroll
        for (int nb = 0; nb < 8; ++nb) {
            const f32x4 p = *(const f32x4*)&sPartF[(((rg * 2 + 1) * 8 + nb) * 64 + lane) * 4];
            acc[1][nb][0] += p[0]; acc[1][nb][1] += p[1];
            acc[1][nb][2] += p[2]; acc[1][nb][3] += p[3];
        }
        #pragma unroll
        for (int r = 0; r < 4; ++r) {
            const float rl = 1.0f / (__shfl(accS1[r], lane & 48)
                                     + sEsrc[rg * 32 + 16 + (lane >> 4) * 4 + r]);
            const int row = g * NN + hf * 256 + rg * 32 + 16 + (lane >> 4) * 4 + r;
            #pragma unroll
            for (int nb = 0; nb < 8; ++nb)
                out[row * FD + nb * 16 + l15] = acc[1][nb][r] * rl;
        }
    }
}

// ---------------------------------------------------------------------------
extern "C" void kernel_launch(void* const* d_in, const int* in_sizes, int n_in,
                              void* d_out, int out_size, void* d_ws, size_t ws_size,
                              hipStream_t stream) {
    const float* h   = (const float*)d_in[0];
    const int*   adj = (const int*)d_in[1];
    const float* W   = (const float*)d_in[2];
    const float* a   = (const float*)d_in[3];
    float* out = (float*)d_out;
    (void)d_ws; (void)ws_size;   // workspace unused — all fused in LDS

    gat_fused_kernel<<<256, 1024, 0, stream>>>(h, a, adj, W, out);
}

// Round 6
// 112.370 us; speedup vs baseline: 1.1607x; 1.1607x over previous
//
#include <hip/hip_runtime.h>
#include <math.h>

typedef __attribute__((ext_vector_type(8))) short bf16x8;
typedef __attribute__((ext_vector_type(4))) float f32x4;

#define MFMA(a, b, c) __builtin_amdgcn_mfma_f32_16x16x32_bf16(a, b, c, 0, 0, 0)

constexpr int GN = 128;   // B*T
constexpr int NN = 512;   // nodes
constexpr int FD = 128;   // F_in == D == 128
#define LOG2E 1.4426950408889634f

// round-to-nearest-even bf16 kept in the TOP 16 bits of a u32
__device__ inline unsigned rne_top16(float x) {
    unsigned u = __float_as_uint(x);
    return u + 0x7fffu + ((u >> 16) & 1u);
}
// pack top-16 of e0 (-> low half) and e1 (-> high half)
__device__ inline unsigned pack_top16(unsigned e1, unsigned e0) {
    return __builtin_amdgcn_perm(e1, e0, 0x07060302u);
}
// async global->LDS, 16 bytes per lane
__device__ inline void gload16(const void* g, void* l) {
    __builtin_amdgcn_global_load_lds(
        (const __attribute__((address_space(1))) unsigned*)g,
        (__attribute__((address_space(3))) unsigned*)l, 16, 0, 0);
}

// ---------------------------------------------------------------------------
// whb (R1 champion, verbatim): block (g, jt): Wh rows jt*128..+128 = h@W via
// 3-split bf16 MFMA. prep fused: W fp32 -> hi/lo bf16 split swizzled into
// LDS; adjacency bitmask row `bid` via two __ballot. h loads issue into
// registers before everything; K-loop barrier-free. Outputs: esrc/edst fp32;
// WhT as SINGLE RNE bf16 in global B-fragment swizzle (elem (j,d) of g at
// g*65536 + ((KK*8+nb)*64+lanep)*8+idx, KK=j>>5, nb=d>>4,
// lanep=(d&15)+16*((j>>3)&3), idx=j&7).
// ---------------------------------------------------------------------------
__global__ __launch_bounds__(256, 2) void whb_kernel(
    const float* __restrict__ h, const float* __restrict__ a,
    const int* __restrict__ adj, const float* __restrict__ W,
    unsigned short* __restrict__ whtHi,
    float* __restrict__ esrc, float* __restrict__ edst,
    unsigned* __restrict__ mask)
{
    __shared__ __attribute__((aligned(16))) unsigned short sW[32768]; // 64 KB

    const int bid = blockIdx.x;
    const int xcd = bid & 7, slot = bid >> 3;
    const int g = xcd + 8 * (slot >> 2);
    const int jt = slot & 3;
    const int t = threadIdx.x, lane = t & 63, w = t >> 6;
    const int i0r = jt * 128;
    const int q8 = (lane >> 4) * 8;
    const float* hg = h + (size_t)(g * NN) * FD;

    // issue all h loads first (registers) — the HBM stream everything hides under
    float4 hv[16];
    #pragma unroll
    for (int kk = 0; kk < 4; ++kk)
        #pragma unroll
        for (int mt = 0; mt < 2; ++mt) {
            const float* src = hg + (size_t)(i0r + w * 32 + mt * 16 + (lane & 15)) * FD
                             + kk * 32 + q8;
            hv[(kk * 2 + mt) * 2 + 0] = *(const float4*)src;
            hv[(kk * 2 + mt) * 2 + 1] = *(const float4*)(src + 4);
        }

    // ---- fused prep (a): adjacency bitmask, one row per block ----
    {
        const int pred0 = adj[bid * NN + t] > 0;
        const int pred1 = adj[bid * NN + 256 + t] > 0;
        const unsigned long long m0 = __ballot(pred0);
        const unsigned long long m1 = __ballot(pred1);
        if (lane == 0) {
            mask[bid * 16 + 2 * w]     = (unsigned)m0;
            mask[bid * 16 + 8 + 2 * w] = (unsigned)m1;
        } else if (lane == 1) {
            mask[bid * 16 + 2 * w + 1]     = (unsigned)(m0 >> 32);
            mask[bid * 16 + 8 + 2 * w + 1] = (unsigned)(m1 >> 32);
        }
    }

    // ---- fused prep (b): W fp32 -> hi/lo bf16 split, swizzled into LDS ----
    #pragma unroll
    for (int grp = 0; grp < 8; ++grp) {
        const int p8 = grp * 256 + t;              // 0..2047 (covers pos=p8*8..+7)
        const int lanep = p8 & 63, cn = p8 >> 6;   // cn 0..31
        const int kks = cn >> 3, nbs = cn & 7;
        const int kbase = kks * 32 + ((lanep >> 4) & 3) * 8;
        const int d = nbs * 16 + (lanep & 15);
        unsigned hi[8], lo[8];
        #pragma unroll
        for (int idx = 0; idx < 8; ++idx) {
            const float wv = W[(kbase + idx) * FD + d];
            const unsigned u = __float_as_uint(wv);
            hi[idx] = u;                            // top16 = truncation
            lo[idx] = rne_top16(wv - __uint_as_float(u & 0xffff0000u));
        }
        uint4 H4, L4;
        H4.x = pack_top16(hi[1], hi[0]); H4.y = pack_top16(hi[3], hi[2]);
        H4.z = pack_top16(hi[5], hi[4]); H4.w = pack_top16(hi[7], hi[6]);
        L4.x = pack_top16(lo[1], lo[0]); L4.y = pack_top16(lo[3], lo[2]);
        L4.z = pack_top16(lo[5], lo[4]); L4.w = pack_top16(lo[7], lo[6]);
        *(uint4*)&sW[p8 * 8]         = H4;
        *(uint4*)&sW[16384 + p8 * 8] = L4;
    }
    __syncthreads();

    f32x4 acc[2][8];
    #pragma unroll
    for (int mt = 0; mt < 2; ++mt)
        #pragma unroll
        for (int nb = 0; nb < 8; ++nb) acc[mt][nb] = (f32x4){0.f, 0.f, 0.f, 0.f};

    #pragma unroll
    for (int kk = 0; kk < 4; ++kk) {
        bf16x8 ah[2], al[2];
        #pragma unroll
        for (int mt = 0; mt < 2; ++mt) {
            const float4 f0 = hv[(kk * 2 + mt) * 2 + 0];
            const float4 f1 = hv[(kk * 2 + mt) * 2 + 1];
            const float xs[8] = {f0.x, f0.y, f0.z, f0.w, f1.x, f1.y, f1.z, f1.w};
            union { bf16x8 v; unsigned u[4]; } H, L;
            #pragma unroll
            for (int j = 0; j < 4; ++j) {
                const unsigned e0 = __float_as_uint(xs[2 * j]);
                const unsigned e1 = __float_as_uint(xs[2 * j + 1]);
                H.u[j] = pack_top16(e1, e0);
                const unsigned l0 = rne_top16(xs[2*j]   - __uint_as_float(e0 & 0xffff0000u));
                const unsigned l1 = rne_top16(xs[2*j+1] - __uint_as_float(e1 & 0xffff0000u));
                L.u[j] = pack_top16(l1, l0);
            }
            ah[mt] = H.v; al[mt] = L.v;
        }
        #pragma unroll
        for (int nb = 0; nb < 8; ++nb) {
            const bf16x8 bh = *(const bf16x8*)&sW[((kk * 8 + nb) * 64 + lane) * 8];
            const bf16x8 bl = *(const bf16x8*)&sW[16384 + ((kk * 8 + nb) * 64 + lane) * 8];
            #pragma unroll
            for (int mt = 0; mt < 2; ++mt) {
                acc[mt][nb] = MFMA(al[mt], bh, acc[mt][nb]);
                acc[mt][nb] = MFMA(ah[mt], bl, acc[mt][nb]);
                acc[mt][nb] = MFMA(ah[mt], bh, acc[mt][nb]);
            }
        }
    }

    // ---- esrc / edst: per-row dot with a_src / a_dst, reduce over 16 lanes ----
    float av[8], bv[8];
    #pragma unroll
    for (int nb = 0; nb < 8; ++nb) {
        av[nb] = a[nb * 16 + (lane & 15)];
        bv[nb] = a[FD + nb * 16 + (lane & 15)];
    }
    #pragma unroll
    for (int mt = 0; mt < 2; ++mt)
        #pragma unroll
        for (int r = 0; r < 4; ++r) {
            float ps = 0.f, pd = 0.f;
            #pragma unroll
            for (int nb = 0; nb < 8; ++nb) {
                ps += acc[mt][nb][r] * av[nb];
                pd += acc[mt][nb][r] * bv[nb];
            }
            #pragma unroll
            for (int off = 1; off <= 8; off <<= 1) {
                ps += __shfl_xor(ps, off);
                pd += __shfl_xor(pd, off);
            }
            if ((lane & 15) == 0) {
                const int row = g * NN + i0r + w * 32 + mt * 16 + (lane >> 4) * 4 + r;
                esrc[row] = ps;
                edst[row] = pd;
            }
        }

    // ---- transpose Wh -> swizzled single RNE bf16, ONE pass (reuse sW) ----
    unsigned short* sT = sW;             // 16384 shorts (32 KB)
    const size_t gbase = (size_t)g * 65536 + (size_t)jt * 16384;
    const int ib = 4 * ((lane >> 4) & 1);

    __syncthreads();                     // everyone done reading sW
    #pragma unroll
    for (int mt = 0; mt < 2; ++mt) {
        const int lp2 = (lane & 15) + 16 * (mt * 2 + (lane >> 5));
        #pragma unroll
        for (int nb = 0; nb < 8; ++nb) {
            const int off = ((w * 8 + nb) * 64 + lp2) * 8 + ib;
            const unsigned r0 = rne_top16(acc[mt][nb][0]);
            const unsigned r1 = rne_top16(acc[mt][nb][1]);
            const unsigned r2 = rne_top16(acc[mt][nb][2]);
            const unsigned r3 = rne_top16(acc[mt][nb][3]);
            *(uint2*)&sT[off] = make_uint2(pack_top16(r1, r0), pack_top16(r3, r2));
        }
    }
    __syncthreads();
    for (int q = t; q < 2048; q += 256)
        *(float4*)&whtHi[gbase + q * 8] = *(const float4*)&sT[q * 8];
}

// ---------------------------------------------------------------------------
// attn: block (g, it): 128 rows (2 row-tiles/wave), grid 512 (2 blocks/CU).
// CHANGE vs R1: chunk size DOUBLED — 2 x 32 KB double-buffered chunks
// (128 j-rows = 16384 shorts each) instead of 2 x 16 KB. Same 74.5 KB LDS
// footprint (2 blocks/CU preserved) but the hot loop crosses only 3
// barrier-drains instead of 7, and each chunk carries 4 KK x 18 MFMAs to
// cover its prefetch. (R5's single-stage attempt mis-sized Wh[g]: it is
// 128 KB, not 64 KB — full staging forces 1 block/CU, the R2/R3 dead end.)
// Chunk-0 staging issues FIRST so eds/maskS/esrc setup hides its latency.
// Loop body is R1's proven interleaved form. B operand is SINGLE bf16 Wh;
// no max-subtraction (shift-invariant; masked -> p = 0 exactly); lsum via
// ones-column MFMA (truncation common-mode preserved).
// ---------------------------------------------------------------------------
__global__ __launch_bounds__(256, 2) void attn_kernel(
    const unsigned short* __restrict__ whtHi,
    const float* __restrict__ esrc, const float* __restrict__ edst,
    const unsigned* __restrict__ mask, float* __restrict__ out)
{
    __shared__ __attribute__((aligned(16))) unsigned short cHi[2][16384];// 64 KB
    __shared__ __attribute__((aligned(16))) float eds[NN];               // 2 KB
    __shared__ unsigned maskS[128 * 17];                                 // 8.5 KB

    const int bid = blockIdx.x;
    const int xcd = bid & 7, slot = bid >> 3;
    const int g = xcd + 8 * (slot >> 2);
    const int it = slot & 3;
    const int t = threadIdx.x, lane = t & 63, w = t >> 6;
    const int i0 = it * 128;
    const int q8 = (lane >> 4) * 8;
    const int l15 = lane & 15;

    // ---- stage chunk 0 (128 j-rows = 16384 shorts = 2048 x 16B) FIRST ----
    const size_t gbase = (size_t)g * 65536;
    for (int q = t; q < 2048; q += 256)
        gload16(&whtHi[gbase + q * 8], &cHi[0][q * 8]);

    // ---- setup while staging streams: eds, maskS, s0/s1 ----
    eds[t]       = edst[g * NN + t] * LOG2E;
    eds[t + 256] = edst[g * NN + 256 + t] * LOG2E;
    for (int q = t; q < 2048; q += 256) {        // 128 rows x 16 words
        const int row = q >> 4, wo = q & 15;
        maskS[row * 17 + wo] = mask[(i0 + row) * 16 + wo];
    }

    const int rloc0 = w * 32 + l15;              // local row in [0,128)
    const int rloc1 = rloc0 + 16;
    const float s0 = esrc[g * NN + i0 + rloc0] * LOG2E;
    const float s1 = esrc[g * NN + i0 + rloc1] * LOG2E;

    // register-constant B fragment: ones in column 0 (lane&15==0), else 0
    union { bf16x8 v; unsigned short s[8]; } bo;
    {
        const unsigned short oneb = (l15 == 0) ? (unsigned short)0x3f80 : (unsigned short)0;
        #pragma unroll
        for (int j = 0; j < 8; ++j) bo.s[j] = oneb;
    }

    __syncthreads();   // covers eds/maskS writes + chunk-0 staging (vmcnt drain)

    f32x4 acc[2][8];
    #pragma unroll
    for (int mt = 0; mt < 2; ++mt)
        #pragma unroll
        for (int nb = 0; nb < 8; ++nb) acc[mt][nb] = (f32x4){0.f, 0.f, 0.f, 0.f};
    f32x4 accS0 = (f32x4){0.f, 0.f, 0.f, 0.f};
    f32x4 accS1 = (f32x4){0.f, 0.f, 0.f, 0.f};

    for (int c4 = 0; c4 < 4; ++c4) {             // 4 chunks x 4 KK each
        const int cur = c4 & 1, nxt = cur ^ 1;
        if (c4 < 3) {                            // prefetch next 32 KB chunk
            const size_t gb = gbase + (size_t)(c4 + 1) * 16384;
            for (int q = t; q < 2048; q += 256)
                gload16(&whtHi[gb + q * 8], &cHi[nxt][q * 8]);
        }
        const unsigned short* __restrict__ bHi = &cHi[cur][0];
        #pragma unroll
        for (int kl = 0; kl < 4; ++kl) {
            const int KK = c4 * 4 + kl;
            const float* ep = &eds[KK * 32 + q8];
            const float4 ed0 = *(const float4*)ep;
            const float4 ed1 = *(const float4*)(ep + 4);
            const float ev[8] = {ed0.x, ed0.y, ed0.z, ed0.w, ed1.x, ed1.y, ed1.z, ed1.w};
            const unsigned mw0 = maskS[rloc0 * 17 + KK] >> q8;
            const unsigned mw1 = maskS[rloc1 * 17 + KK] >> q8;

            union { bf16x8 v; unsigned u[4]; } H0, H1;
            unsigned uh0[8], uh1[8];
            #pragma unroll
            for (int i = 0; i < 8; ++i) {
                const float z0 = s0 + ev[i];
                float p0 = __builtin_amdgcn_exp2f(fmaxf(z0, 0.2f * z0));
                p0 = ((mw0 >> i) & 1u) ? p0 : 0.f;
                uh0[i] = __float_as_uint(p0);
                const float z1 = s1 + ev[i];
                float p1 = __builtin_amdgcn_exp2f(fmaxf(z1, 0.2f * z1));
                p1 = ((mw1 >> i) & 1u) ? p1 : 0.f;
                uh1[i] = __float_as_uint(p1);
            }
            #pragma unroll
            for (int j = 0; j < 4; ++j) {
                H0.u[j] = pack_top16(uh0[2*j+1], uh0[2*j]);   // perm keeps top16 = trunc
                H1.u[j] = pack_top16(uh1[2*j+1], uh1[2*j]);
            }
            #pragma unroll
            for (int nb = 0; nb < 8; ++nb) {
                const bf16x8 bh = *(const bf16x8*)&bHi[((kl * 8 + nb) * 64 + lane) * 8];
                acc[0][nb] = MFMA(H0.v, bh, acc[0][nb]);
                acc[1][nb] = MFMA(H1.v, bh, acc[1][nb]);
            }
            accS0 = MFMA(H0.v, bo.v, accS0);       // row-sums (lsum) in column 0
            accS1 = MFMA(H1.v, bo.v, accS1);
        }
        __syncthreads();   // all waves done with cur; prefetch into nxt landed
    }

    #pragma unroll
    for (int r = 0; r < 4; ++r) {
        // lsum for output row rr=(lane>>4)*4+r sits at lane (lane&48), reg r, col 0
        const float rl0 = 1.0f / __shfl(accS0[r], lane & 48);
        const float rl1 = 1.0f / __shfl(accS1[r], lane & 48);
        const int row0 = g * NN + i0 + w * 32 + (lane >> 4) * 4 + r;
        const int row1 = row0 + 16;
        #pragma unroll
        for (int nb = 0; nb < 8; ++nb) {
            out[row0 * FD + nb * 16 + l15] = acc[0][nb][r] * rl0;
            out[row1 * FD + nb * 16 + l15] = acc[1][nb][r] * rl1;
        }
    }
}

// ---------------------------------------------------------------------------
extern "C" void kernel_launch(void* const* d_in, const int* in_sizes, int n_in,
                              void* d_out, int out_size, void* d_ws, size_t ws_size,
                              hipStream_t stream) {
    const float* h   = (const float*)d_in[0];
    const int*   adj = (const int*)d_in[1];
    const float* W   = (const float*)d_in[2];
    const float* a   = (const float*)d_in[3];
    float* out = (float*)d_out;

    unsigned short* whtHi = (unsigned short*)d_ws;                       // 16.78 MB
    float* esrc = (float*)(whtHi + (size_t)GN * 65536);                  // 256 KB
    float* edst = esrc + GN * NN;                                        // 256 KB
    unsigned* mask = (unsigned*)(edst + GN * NN);                        // 32 KB

    whb_kernel<<<512, 256, 0, stream>>>(h, a, adj, W, whtHi, esrc, edst, mask);
    attn_kernel<<<512, 256, 0, stream>>>(whtHi, esrc, edst, mask, out);
}